// Round 14
// baseline (90.530 us; speedup 1.0000x reference)
//
#include <hip/hip_runtime.h>
#include <hip/hip_bf16.h>

typedef __bf16 bf16;
typedef __bf16 bf16x4 __attribute__((ext_vector_type(4)));
typedef __bf16 bf16x8 __attribute__((ext_vector_type(8)));
typedef float  f32x16 __attribute__((ext_vector_type(16)));

#define MFMA32 __builtin_amdgcn_mfma_f32_32x32x16_bf16
#define EPSV 1e-5f
#define QSCALE 0.36067376022224085f  /* 0.25 * log2(e) */

__device__ __forceinline__ f32x16 fzero16() {
  f32x16 z;
#pragma unroll
  for (int i = 0; i < 16; ++i) z[i] = 0.f;
  return z;
}

/* async 16B/lane global->LDS DMA (m97 pattern): lds dst = uniform base +
   lane*16; global src is per-lane. Compiler-known side effect — cannot sink. */
__device__ __forceinline__ void dma16(const void* g, void* s) {
  __builtin_amdgcn_global_load_lds(
      (const __attribute__((address_space(1))) void*)g,
      (__attribute__((address_space(3))) void*)s, 16, 0, 0);
}

/* ---------------- kernel 1a: per-batch partial sums over x1 ---------------- */
__global__ __launch_bounds__(256) void k_stats_partial(const float* __restrict__ x,
                                                       float* __restrict__ part) {
  const int b = blockIdx.x >> 5, k = blockIdx.x & 31;
  const float* p = x + (size_t)b * 256 * 4096 + k * 8192;
  const int t = threadIdx.x;
  float s = 0.f, q = 0.f;
#pragma unroll
  for (int j = 0; j < 8; ++j) {
    float4 v = ((const float4*)p)[t + j * 256];
    s += v.x + v.y + v.z + v.w;
    q += v.x * v.x + v.y * v.y + v.z * v.z + v.w * v.w;
  }
  __shared__ float ls[256], lq[256];
  ls[t] = s; lq[t] = q;
  __syncthreads();
  for (int off = 128; off > 0; off >>= 1) {
    if (t < off) { ls[t] += ls[t + off]; lq[t] += lq[t + off]; }
    __syncthreads();
  }
  if (t == 0) { part[blockIdx.x * 2] = ls[0]; part[blockIdx.x * 2 + 1] = lq[0]; }
}

/* ---------------- kernel 1b: finalize mu / rstd per batch ---------------- */
__global__ __launch_bounds__(256) void k_stats_final(const float* __restrict__ part,
                                                     float* __restrict__ stats) {
  const int t = threadIdx.x, b = t >> 5, k = t & 31;
  float s = part[(b * 32 + k) * 2], q = part[(b * 32 + k) * 2 + 1];
  for (int off = 16; off > 0; off >>= 1) {
    s += __shfl_down(s, off, 32);
    q += __shfl_down(q, off, 32);
  }
  if (k == 0) {
    const float inv_n = 1.f / 262144.f;
    const float mu = s * inv_n;
    const float var = q * inv_n - mu * mu;
    stats[b * 2] = mu;
    stats[b * 2 + 1] = rsqrtf(var + EPSV);
  }
}

/* ------- kernel 2: GN-normalize x1, qkv matmul + BN, emit q/k/v bf16 -------
   V written in MFMA-FRAGMENT-MAJOR layout: vf[IT][f][lane][16B], where
   slot j of lane l = V[c=(l&31)+32*(f&1)][m=(j&3)+4*(l>>5)+8*(j>>2)+16*(f>>1)]
   (IT = global 32-key tile). Attention then loads V fully coalesced.        */
__global__ __launch_bounds__(256) void k_qkv(
    const float* __restrict__ x, const float* __restrict__ gn_g, const float* __restrict__ gn_b,
    const float* __restrict__ qkv_w, const float* __restrict__ bn_g, const float* __restrict__ bn_b,
    const float* __restrict__ bn_rm, const float* __restrict__ bn_rv,
    const float* __restrict__ stats,
    bf16* __restrict__ qw, bf16* __restrict__ kw, bf16* __restrict__ vw) {
  const int b = blockIdx.x >> 6, tile = blockIdx.x & 63;
  const int n0 = tile * 64, t = threadIdx.x;
  __shared__ float xn[64][68];
  __shared__ float W[64][96];
  __shared__ float beta_s[96];
  const float mu = stats[b * 2], rstd = stats[b * 2 + 1];
  {
    const int c = t >> 2, f = t & 3;
    const float A = rstd * gn_g[c], B = gn_b[c] - mu * A;
    const float* xr = x + ((size_t)b * 256 + c) * 4096 + n0;
#pragma unroll
    for (int j = 0; j < 4; ++j) {
      float4 v = ((const float4*)xr)[f * 4 + j];
      const int nb = f * 16 + j * 4;
      xn[c][nb + 0] = v.x * A + B; xn[c][nb + 1] = v.y * A + B;
      xn[c][nb + 2] = v.z * A + B; xn[c][nb + 3] = v.w * A + B;
    }
  }
  for (int oc = t; oc < 96 * 8; oc += 256) {
    const int o = oc >> 3, ch = (oc & 7) * 8;
    const float inv = bn_g[o] * rsqrtf(bn_rv[o] + EPSV);
    if (ch == 0) beta_s[o] = bn_b[o] - bn_rm[o] * inv;
    const float* wr = qkv_w + o * 64 + ch;
#pragma unroll
    for (int i = 0; i < 8; ++i) W[ch + i][o] = wr[i] * inv;
  }
  __syncthreads();
  const int o_l = t & 31, ng = t >> 5;
#pragma unroll 1
  for (int p = 0; p < 3; ++p) {
    const int o = p * 32 + o_l;
    float acc[8];
#pragma unroll
    for (int j = 0; j < 8; ++j) acc[j] = 0.f;
    for (int c = 0; c < 64; ++c) {
      const float wv = W[c][o];
      const float* xr = &xn[c][ng * 8];
#pragma unroll
      for (int j = 0; j < 8; ++j) acc[j] += wv * xr[j];
    }
    const float beta = beta_s[o];
    const int nb = n0 + ng * 8;
    if (p == 0) {
      if (o < 16) {
#pragma unroll
        for (int j = 0; j < 8; ++j)
          qw[((size_t)b * 4096 + nb + j) * 16 + o] = (bf16)((acc[j] + beta) * QSCALE);
      } else {
#pragma unroll
        for (int j = 0; j < 8; ++j)
          kw[((size_t)b * 4096 + nb + j) * 16 + (o - 16)] = (bf16)(acc[j] + beta);
      }
    } else {
      const int c = (p - 1) * 32 + o_l;
      /* fragment-major V store: thread owns (c, keys nb..nb+7) */
      const int IT = nb >> 5;             /* global 32-key tile   */
      const int m4 = nb & 31;             /* 0,8,16,24            */
      const int f  = ((m4 >> 4) << 1) + (c >> 5);
      const int b3 = (m4 >> 3) & 1;
      char* base = (char*)vw + (size_t)b * 524288 + (size_t)IT * 4096 +
                   f * 1024 + (c & 31) * 16 + b3 * 8;
      bf16x4 pk0, pk1;
#pragma unroll
      for (int i = 0; i < 4; ++i) {
        pk0[i] = (bf16)(acc[i] + beta);       /* keys m4..m4+3  -> lane c&31      */
        pk1[i] = (bf16)(acc[4 + i] + beta);   /* keys m4+4..+7  -> lane (c&31)+32 */
      }
      *(bf16x4*)base = pk0;
      *(bf16x4*)(base + 512) = pk1;
    }
  }
}

/* --------------- kernel 3: flash attention, async-DMA pipeline --------------
   grid 1024 (XCD-swizzled, batch-per-XCD); 256 thr = 4 waves = 4 key-ranges
   of 1024 keys, all for the SAME 32 queries (4 blocks/CU via 40KB LDS).
   Main loop: per-wave 2-slot LDS ring (K 1KB + V 4KB per 32-key tile),
   filled by async global_load_lds (compiler cannot sink — fixes R10-12 where
   plain-load prefetch was deleted, VGPR=60), counted s_waitcnt vmcnt(5)
   (T4), ds_read_b128 fragments, lgkmcnt(0) guard before slot reuse.
   End: in-LDS 4-way split-K combine + fused relu(x2) transpose.              */
__global__ __launch_bounds__(256, 4) void k_attn(
    const bf16* __restrict__ qw, const bf16* __restrict__ kw,
    const bf16* __restrict__ vw, const float* __restrict__ x,
    bf16* __restrict__ xc) {
  __shared__ __align__(16) char smem[40960];   /* 4 waves x 2 slots x 5KB */
  const int orig = blockIdx.x;
  const int wg = (orig & 7) * 128 + (orig >> 3);  /* XCD j <- batch j */
  const int b = wg >> 7, qblk = wg & 127;
  const int t = threadIdx.x;
  const int wid = t >> 6, l = t & 63, ln = l & 31, g = l >> 5;
  const int m0 = wid * 1024;

  const bf16* qb = qw + (size_t)b * 4096 * 16;
  const char* kb = (const char*)(kw + (size_t)b * 4096 * 16);
  const char* vfb = (const char*)vw + (size_t)b * 524288;

  /* per-lane DMA source bases (fragment permutation lives in the source) */
  const char* kdma = kb + (size_t)m0 * 32 + (2 * ln + g) * 16;
  const char* vdma = vfb + (size_t)(m0 >> 5) * 4096 + l * 16;
  char* ring = smem + wid * 10240;

  const int nq = qblk * 32 + ln;
  const bf16x8 qf = *(const bf16x8*)(qb + (size_t)nq * 16 + g * 8);
  asm volatile("" :: "v"(qf));   /* force qf's vmcnt wait BEFORE the pipeline */

  f32x16 O0 = fzero16(), O1 = fzero16();
  float l_run = 0.f;

  /* prologue: tiles 0,1 in flight (5 DMAs each -> vmcnt 10 outstanding) */
#pragma unroll
  for (int pt = 0; pt < 2; ++pt) {
    char* dst = ring + pt * 5120;
    const char* ks = kdma + (size_t)pt * 1024;
    const char* vs = vdma + (size_t)pt * 4096;
    dma16(ks, dst);
    dma16(vs, dst + 1024);
    dma16(vs + 1024, dst + 2048);
    dma16(vs + 2048, dst + 3072);
    dma16(vs + 3072, dst + 4096);
  }

#pragma unroll 1
  for (int it = 0; it < 32; ++it) {
    if (it < 31) { asm volatile("s_waitcnt vmcnt(5)" ::: "memory"); }
    else         { asm volatile("s_waitcnt vmcnt(0)" ::: "memory"); }
    const char* rb = ring + (it & 1) * 5120 + l * 16;
    const uint4 kc = *(const uint4*)rb;
    const uint4 v0 = *(const uint4*)(rb + 1024);
    const uint4 v1 = *(const uint4*)(rb + 2048);
    const uint4 v2 = *(const uint4*)(rb + 3072);
    const uint4 v3 = *(const uint4*)(rb + 4096);
    /* QK^T: S[key m][query n], n = ln lane-local */
    f32x16 S = MFMA32(__builtin_bit_cast(bf16x8, kc), qf, fzero16(), 0, 0, 0);
    float ts = 0.f;
#pragma unroll
    for (int r = 0; r < 16; ++r) { S[r] = __builtin_amdgcn_exp2f(S[r]); ts += S[r]; }
    l_run += ts;                 /* shfl merge deferred to after loop */
    bf16x8 pb0, pb1;
#pragma unroll
    for (int r = 0; r < 8; ++r) { pb0[r] = (bf16)S[r]; pb1[r] = (bf16)S[r + 8]; }
    O0 = MFMA32(__builtin_bit_cast(bf16x8, v0), pb0, O0, 0, 0, 0);
    O1 = MFMA32(__builtin_bit_cast(bf16x8, v1), pb0, O1, 0, 0, 0);
    O0 = MFMA32(__builtin_bit_cast(bf16x8, v2), pb1, O0, 0, 0, 0);
    O1 = MFMA32(__builtin_bit_cast(bf16x8, v3), pb1, O1, 0, 0, 0);
    /* ds_reads of this slot fully retired before the DMA may overwrite it */
    asm volatile("s_waitcnt lgkmcnt(0)" ::: "memory");
    if (it + 2 < 32) {
      char* dst = ring + (it & 1) * 5120;
      const char* ks = kdma + (size_t)(it + 2) * 1024;
      const char* vs = vdma + (size_t)(it + 2) * 4096;
      dma16(ks, dst);
      dma16(vs, dst + 1024);
      dma16(vs + 1024, dst + 2048);
      dma16(vs + 2048, dst + 3072);
      dma16(vs + 3072, dst + 4096);
    }
  }
  l_run += __shfl_xor(l_run, 32, 64);

  __syncthreads();   /* ring traffic done block-wide; reuse LDS for combine */

  /* partials into own LDS slice: Opart[wid][n 32][16 x 8B chunks] swizzled */
  {
    char* orow = smem + wid * 4096 + ln * 128;
    const int msk = 2 * (ln & 7);
#pragma unroll
    for (int h = 0; h < 2; ++h) {
      const f32x16& O = h ? O1 : O0;
#pragma unroll
      for (int j = 0; j < 4; ++j) {
        bf16x4 e;
#pragma unroll
        for (int i = 0; i < 4; ++i) e[i] = (bf16)O[4 * j + i];
        const int chunk = h * 8 + 2 * j + g;
        *(bf16x4*)(orow + ((chunk ^ msk) << 3)) = e;
      }
    }
    if (g == 0) *(float*)(smem + 16384 + wid * 128 + ln * 4) = l_run;
  }
  __syncthreads();

  /* combine 4 key-range partials -> xc[:,0:64]; thread owns (n, 16B chunk) */
  {
    const int n = t >> 3, k8 = t & 7;
    const int off = ((2 * k8) ^ (2 * (n & 7))) << 3;
    float L = 0.f;
    float acc[8];
#pragma unroll
    for (int e = 0; e < 8; ++e) acc[e] = 0.f;
#pragma unroll
    for (int kr_ = 0; kr_ < 4; ++kr_) {
      L += *(const float*)(smem + 16384 + kr_ * 128 + n * 4);
      const bf16x8 v = *(const bf16x8*)(smem + kr_ * 4096 + n * 128 + off);
#pragma unroll
      for (int e = 0; e < 8; ++e) acc[e] += (float)v[e];
    }
    const float rL = 1.0f / L;
    bf16x8 o8;
#pragma unroll
    for (int e = 0; e < 8; ++e) o8[e] = (bf16)fmaxf(acc[e] * rL, 0.f);
    *(bf16x8*)(xc + ((size_t)b * 4096 + qblk * 32 + n) * 256 + k8 * 8) = o8;
  }
  __syncthreads();

  /* fused prep_x2: relu(x2) -> bf16 transpose into xc[n][64:256] (32 rows) */
  {
    unsigned* tile_u = (unsigned*)smem;  /* [32 n][97 stride] words */
    const float* xb = x + ((size_t)b * 256 + 64) * 4096 + qblk * 32;
#pragma unroll
    for (int i = 0; i < 3; ++i) {
      const int idx = i * 256 + t;
      const int cp = idx >> 3, f = idx & 7;
      const float4 a = *(const float4*)(xb + (size_t)(2 * cp) * 4096 + f * 4);
      const float4 c4 = *(const float4*)(xb + (size_t)(2 * cp + 1) * 4096 + f * 4);
      const float av[4] = {a.x, a.y, a.z, a.w};
      const float cv[4] = {c4.x, c4.y, c4.z, c4.w};
#pragma unroll
      for (int e = 0; e < 4; ++e) {
        const unsigned u =
            (unsigned)__builtin_bit_cast(unsigned short, (bf16)fmaxf(av[e], 0.f)) |
            ((unsigned)__builtin_bit_cast(unsigned short, (bf16)fmaxf(cv[e], 0.f)) << 16);
        tile_u[(f * 4 + e) * 97 + cp] = u;
      }
    }
    __syncthreads();
#pragma unroll
    for (int i = 0; i < 3; ++i) {
      const int idx = i * 256 + t;
      const int n = idx / 24, q = idx % 24;
      const uint4 d = *(const uint4*)&tile_u[n * 97 + q * 4];
      *(uint4*)(xc + ((size_t)b * 4096 + qblk * 32 + n) * 256 + 64 + q * 8) = d;
    }
  }
}

/* ---------- kernel 4: proj matmul (MFMA bf16) + BN, 128n x 128o tile ---------- */
__global__ __launch_bounds__(256, 2) void k_proj(
    const bf16* __restrict__ xc, const float* __restrict__ pw,
    const float* __restrict__ bn_g, const float* __restrict__ bn_b,
    const float* __restrict__ bn_rm, const float* __restrict__ bn_rv,
    float* __restrict__ out) {
  const int orig = blockIdx.x;
  const int wg = (orig & 7) * 64 + (orig >> 3);  /* XCD swizzle, 512 blocks */
  const int b = wg >> 6, rem = wg & 63, nt = rem >> 1, oh = rem & 1;
  const int n0 = nt * 128, o0 = oh * 128;
  const int t = threadIdx.x, w = t >> 6, l = t & 63, ln = l & 31, g = l >> 5;

  __shared__ __align__(16) bf16 pws[128 * 256];
  __shared__ float beta_s[128];

  {
    const int o = t >> 1, half = t & 1;
    const float inv = bn_g[o0 + o] * rsqrtf(bn_rv[o0 + o] + EPSV);
    if (half == 0) beta_s[o] = bn_b[o0 + o] - bn_rm[o0 + o] * inv;
    const float* wr = pw + (size_t)(o0 + o) * 256 + half * 128;
    const int s_hh = (o & 15) * 8;
#pragma unroll
    for (int j = 0; j < 16; ++j) {
      const float4 a = ((const float4*)wr)[j * 2];
      const float4 c4 = ((const float4*)wr)[j * 2 + 1];
      bf16x8 v8;
      v8[0] = (bf16)(a.x * inv);  v8[1] = (bf16)(a.y * inv);
      v8[2] = (bf16)(a.z * inv);  v8[3] = (bf16)(a.w * inv);
      v8[4] = (bf16)(c4.x * inv); v8[5] = (bf16)(c4.y * inv);
      v8[6] = (bf16)(c4.z * inv); v8[7] = (bf16)(c4.w * inv);
      *(bf16x8*)&pws[o * 256 + ((half * 128 + j * 8) ^ s_hh)] = v8;
    }
  }
  __syncthreads();

  const bf16* xrow = xc + ((size_t)b * 4096 + n0 + w * 32 + ln) * 256;
  const int sw = (ln & 15) * 8;
  f32x16 acc0 = fzero16(), acc1 = fzero16(), acc2 = fzero16(), acc3 = fzero16();
#pragma unroll 4
  for (int ck = 0; ck < 256; ck += 16) {
    const bf16x8 bfrag = *(const bf16x8*)(xrow + ck + g * 8);
    const int cidx = (ck + g * 8) ^ sw;
    const bf16x8 a0 = *(const bf16x8*)&pws[(ln) * 256 + cidx];
    const bf16x8 a1 = *(const bf16x8*)&pws[(32 + ln) * 256 + cidx];
    const bf16x8 a2 = *(const bf16x8*)&pws[(64 + ln) * 256 + cidx];
    const bf16x8 a3 = *(const bf16x8*)&pws[(96 + ln) * 256 + cidx];
    acc0 = MFMA32(a0, bfrag, acc0, 0, 0, 0);
    acc1 = MFMA32(a1, bfrag, acc1, 0, 0, 0);
    acc2 = MFMA32(a2, bfrag, acc2, 0, 0, 0);
    acc3 = MFMA32(a3, bfrag, acc3, 0, 0, 0);
  }
  const int ncol = n0 + w * 32 + ln;
  float* ob = out + (size_t)b * 256 * 4096 + ncol;
#pragma unroll
  for (int og = 0; og < 4; ++og) {
    const f32x16& A = og == 0 ? acc0 : og == 1 ? acc1 : og == 2 ? acc2 : acc3;
#pragma unroll
    for (int r = 0; r < 16; ++r) {
      const int o_loc = og * 32 + (r & 3) + 8 * (r >> 2) + 4 * g;
      ob[(size_t)(o0 + o_loc) * 4096] = A[r] + beta_s[o_loc];
    }
  }
}

/* ---------------- host launcher ---------------- */
extern "C" void kernel_launch(void* const* d_in, const int* in_sizes, int n_in,
                              void* d_out, int out_size, void* d_ws, size_t ws_size,
                              hipStream_t stream) {
  (void)in_sizes; (void)n_in; (void)out_size; (void)ws_size;
  const float* x        = (const float*)d_in[0];
  const float* gn_g     = (const float*)d_in[1];
  const float* gn_b     = (const float*)d_in[2];
  const float* qkv_w    = (const float*)d_in[3];
  const float* qkv_bn_g = (const float*)d_in[4];
  const float* qkv_bn_b = (const float*)d_in[5];
  const float* qkv_rm   = (const float*)d_in[6];
  const float* qkv_rv   = (const float*)d_in[7];
  const float* proj_w   = (const float*)d_in[8];
  const float* proj_bn_g = (const float*)d_in[9];
  const float* proj_bn_b = (const float*)d_in[10];
  const float* proj_rm  = (const float*)d_in[11];
  const float* proj_rv  = (const float*)d_in[12];

  char* ws = (char*)d_ws;
  float* part  = (float*)ws;
  float* stats = (float*)(ws + 4096);
  bf16* qw = (bf16*)(ws + 8192);
  bf16* kw = (bf16*)(ws + 8192 + (1u << 20));
  bf16* vw = (bf16*)(ws + 8192 + (2u << 20));
  bf16* xc = (bf16*)(ws + 8192 + (6u << 20));

  k_stats_partial<<<256, 256, 0, stream>>>(x, part);
  k_stats_final<<<1, 256, 0, stream>>>(part, stats);
  k_qkv<<<512, 256, 0, stream>>>(x, gn_g, gn_b, qkv_w, qkv_bn_g, qkv_bn_b,
                                 qkv_rm, qkv_rv, stats, qw, kw, vw);
  k_attn<<<1024, 256, 0, stream>>>(qw, kw, vw, x, xc);
  k_proj<<<512, 256, 0, stream>>>(xc, proj_w, proj_bn_g, proj_bn_b,
                                  proj_rm, proj_rv, (float*)d_out);
}

// Round 15
// 87.482 us; speedup vs baseline: 1.0348x; 1.0348x over previous
//
#include <hip/hip_runtime.h>
#include <hip/hip_bf16.h>

typedef __bf16 bf16;
typedef __bf16 bf16x4 __attribute__((ext_vector_type(4)));
typedef __bf16 bf16x8 __attribute__((ext_vector_type(8)));
typedef float  f32x16 __attribute__((ext_vector_type(16)));

#define MFMA32 __builtin_amdgcn_mfma_f32_32x32x16_bf16
#define EPSV 1e-5f
#define QSCALE 0.36067376022224085f  /* 0.25 * log2(e) */

__device__ __forceinline__ f32x16 fzero16() {
  f32x16 z;
#pragma unroll
  for (int i = 0; i < 16; ++i) z[i] = 0.f;
  return z;
}

/* async 16B/lane global->LDS DMA (m97 pattern): lds dst = uniform base +
   lane*16; global src is per-lane. Compiler-known side effect — cannot sink. */
__device__ __forceinline__ void dma16(const void* g, void* s) {
  __builtin_amdgcn_global_load_lds(
      (const __attribute__((address_space(1))) void*)g,
      (__attribute__((address_space(3))) void*)s, 16, 0, 0);
}

/* ---------------- kernel 1a: per-batch partial sums over x1 ---------------- */
__global__ __launch_bounds__(256) void k_stats_partial(const float* __restrict__ x,
                                                       float* __restrict__ part) {
  const int b = blockIdx.x >> 5, k = blockIdx.x & 31;
  const float* p = x + (size_t)b * 256 * 4096 + k * 8192;
  const int t = threadIdx.x;
  float s = 0.f, q = 0.f;
#pragma unroll
  for (int j = 0; j < 8; ++j) {
    float4 v = ((const float4*)p)[t + j * 256];
    s += v.x + v.y + v.z + v.w;
    q += v.x * v.x + v.y * v.y + v.z * v.z + v.w * v.w;
  }
  __shared__ float ls[256], lq[256];
  ls[t] = s; lq[t] = q;
  __syncthreads();
  for (int off = 128; off > 0; off >>= 1) {
    if (t < off) { ls[t] += ls[t + off]; lq[t] += lq[t + off]; }
    __syncthreads();
  }
  if (t == 0) { part[blockIdx.x * 2] = ls[0]; part[blockIdx.x * 2 + 1] = lq[0]; }
}

/* ---------------- kernel 1b: finalize mu / rstd per batch ---------------- */
__global__ __launch_bounds__(256) void k_stats_final(const float* __restrict__ part,
                                                     float* __restrict__ stats) {
  const int t = threadIdx.x, b = t >> 5, k = t & 31;
  float s = part[(b * 32 + k) * 2], q = part[(b * 32 + k) * 2 + 1];
  for (int off = 16; off > 0; off >>= 1) {
    s += __shfl_down(s, off, 32);
    q += __shfl_down(q, off, 32);
  }
  if (k == 0) {
    const float inv_n = 1.f / 262144.f;
    const float mu = s * inv_n;
    const float var = q * inv_n - mu * mu;
    stats[b * 2] = mu;
    stats[b * 2 + 1] = rsqrtf(var + EPSV);
  }
}

/* ------- kernel 2: GN-normalize x1, qkv matmul + BN, emit q/k/v bf16 -------
   V written in MFMA-FRAGMENT-MAJOR layout: vf[IT][f][lane][16B], where
   slot j of lane l = V[c=(l&31)+32*(f&1)][m=(j&3)+4*(l>>5)+8*(j>>2)+16*(f>>1)]
   (IT = global 32-key tile). Attention then loads V fully coalesced.        */
__global__ __launch_bounds__(256) void k_qkv(
    const float* __restrict__ x, const float* __restrict__ gn_g, const float* __restrict__ gn_b,
    const float* __restrict__ qkv_w, const float* __restrict__ bn_g, const float* __restrict__ bn_b,
    const float* __restrict__ bn_rm, const float* __restrict__ bn_rv,
    const float* __restrict__ stats,
    bf16* __restrict__ qw, bf16* __restrict__ kw, bf16* __restrict__ vw) {
  const int b = blockIdx.x >> 6, tile = blockIdx.x & 63;
  const int n0 = tile * 64, t = threadIdx.x;
  __shared__ float xn[64][68];
  __shared__ float W[64][96];
  __shared__ float beta_s[96];
  const float mu = stats[b * 2], rstd = stats[b * 2 + 1];
  {
    const int c = t >> 2, f = t & 3;
    const float A = rstd * gn_g[c], B = gn_b[c] - mu * A;
    const float* xr = x + ((size_t)b * 256 + c) * 4096 + n0;
#pragma unroll
    for (int j = 0; j < 4; ++j) {
      float4 v = ((const float4*)xr)[f * 4 + j];
      const int nb = f * 16 + j * 4;
      xn[c][nb + 0] = v.x * A + B; xn[c][nb + 1] = v.y * A + B;
      xn[c][nb + 2] = v.z * A + B; xn[c][nb + 3] = v.w * A + B;
    }
  }
  for (int oc = t; oc < 96 * 8; oc += 256) {
    const int o = oc >> 3, ch = (oc & 7) * 8;
    const float inv = bn_g[o] * rsqrtf(bn_rv[o] + EPSV);
    if (ch == 0) beta_s[o] = bn_b[o] - bn_rm[o] * inv;
    const float* wr = qkv_w + o * 64 + ch;
#pragma unroll
    for (int i = 0; i < 8; ++i) W[ch + i][o] = wr[i] * inv;
  }
  __syncthreads();
  const int o_l = t & 31, ng = t >> 5;
#pragma unroll 1
  for (int p = 0; p < 3; ++p) {
    const int o = p * 32 + o_l;
    float acc[8];
#pragma unroll
    for (int j = 0; j < 8; ++j) acc[j] = 0.f;
    for (int c = 0; c < 64; ++c) {
      const float wv = W[c][o];
      const float* xr = &xn[c][ng * 8];
#pragma unroll
      for (int j = 0; j < 8; ++j) acc[j] += wv * xr[j];
    }
    const float beta = beta_s[o];
    const int nb = n0 + ng * 8;
    if (p == 0) {
      if (o < 16) {
#pragma unroll
        for (int j = 0; j < 8; ++j)
          qw[((size_t)b * 4096 + nb + j) * 16 + o] = (bf16)((acc[j] + beta) * QSCALE);
      } else {
#pragma unroll
        for (int j = 0; j < 8; ++j)
          kw[((size_t)b * 4096 + nb + j) * 16 + (o - 16)] = (bf16)(acc[j] + beta);
      }
    } else {
      const int c = (p - 1) * 32 + o_l;
      /* fragment-major V store: thread owns (c, keys nb..nb+7) */
      const int IT = nb >> 5;             /* global 32-key tile   */
      const int m4 = nb & 31;             /* 0,8,16,24            */
      const int f  = ((m4 >> 4) << 1) + (c >> 5);
      const int b3 = (m4 >> 3) & 1;
      char* base = (char*)vw + (size_t)b * 524288 + (size_t)IT * 4096 +
                   f * 1024 + (c & 31) * 16 + b3 * 8;
      bf16x4 pk0, pk1;
#pragma unroll
      for (int i = 0; i < 4; ++i) {
        pk0[i] = (bf16)(acc[i] + beta);       /* keys m4..m4+3  -> lane c&31      */
        pk1[i] = (bf16)(acc[4 + i] + beta);   /* keys m4+4..+7  -> lane (c&31)+32 */
      }
      *(bf16x4*)base = pk0;
      *(bf16x4*)(base + 512) = pk1;
    }
  }
}

/* ------- kernel 3: flash attention, async-DMA pipeline, 64 queries/wave -----
   grid 512 (XCD-swizzled, batch-per-XCD); 256 thr = 4 waves = 4 key-ranges
   of 1024 keys, ALL for the SAME 64 queries (2 q-fragments per wave sharing
   every K/V byte -> L2 traffic halved vs R14, and TWO independent S-chains
   per wave -> in-wave ILP doubles, compensating low occupancy).
   Loop: per-wave 2-slot LDS ring filled by async global_load_lds (cannot
   sink), counted s_waitcnt vmcnt(5), ds_read_b128 fragments, lgkmcnt(0)
   guard. End: in-LDS 8-slice split-K combine + fused relu(x2) transpose.     */
__global__ __launch_bounds__(256, 2) void k_attn(
    const bf16* __restrict__ qw, const bf16* __restrict__ kw,
    const bf16* __restrict__ vw, const float* __restrict__ x,
    bf16* __restrict__ xc) {
  __shared__ __align__(16) char smem[40960];   /* 4 waves x 2 slots x 5KB */
  const int orig = blockIdx.x;
  const int wg = (orig & 7) * 64 + (orig >> 3);  /* XCD j <- batch j */
  const int b = wg >> 6, qblk = wg & 63;
  const int t = threadIdx.x;
  const int wid = t >> 6, l = t & 63, ln = l & 31, g = l >> 5;
  const int m0 = wid * 1024;

  const bf16* qb = qw + (size_t)b * 4096 * 16;
  const char* kb = (const char*)(kw + (size_t)b * 4096 * 16);
  const char* vfb = (const char*)vw + (size_t)b * 524288;

  /* per-lane DMA source bases (fragment permutation lives in the source) */
  const char* kdma = kb + (size_t)m0 * 32 + (2 * ln + g) * 16;
  const char* vdma = vfb + (size_t)(m0 >> 5) * 4096 + l * 16;
  char* ring = smem + wid * 10240;

  const int nq = qblk * 64 + ln;
  const bf16x8 qf0 = *(const bf16x8*)(qb + (size_t)nq * 16 + g * 8);
  const bf16x8 qf1 = *(const bf16x8*)(qb + (size_t)(nq + 32) * 16 + g * 8);
  asm volatile("" :: "v"(qf0), "v"(qf1));  /* resolve q before the pipeline */

  f32x16 O00 = fzero16(), O01 = fzero16();  /* q-sub 0: c 0-31 / 32-63 */
  f32x16 O10 = fzero16(), O11 = fzero16();  /* q-sub 1 */
  float l0 = 0.f, l1 = 0.f;

  /* prologue: tiles 0,1 in flight (5 DMAs each -> vmcnt 10 outstanding) */
#pragma unroll
  for (int pt = 0; pt < 2; ++pt) {
    char* dst = ring + pt * 5120;
    const char* ks = kdma + (size_t)pt * 1024;
    const char* vs = vdma + (size_t)pt * 4096;
    dma16(ks, dst);
    dma16(vs, dst + 1024);
    dma16(vs + 1024, dst + 2048);
    dma16(vs + 2048, dst + 3072);
    dma16(vs + 3072, dst + 4096);
  }

#pragma unroll 1
  for (int it = 0; it < 32; ++it) {
    if (it < 31) { asm volatile("s_waitcnt vmcnt(5)" ::: "memory"); }
    else         { asm volatile("s_waitcnt vmcnt(0)" ::: "memory"); }
    const char* rb = ring + (it & 1) * 5120 + l * 16;
    const uint4 kc = *(const uint4*)rb;
    const uint4 v0 = *(const uint4*)(rb + 1024);
    const uint4 v1 = *(const uint4*)(rb + 2048);
    const uint4 v2 = *(const uint4*)(rb + 3072);
    const uint4 v3 = *(const uint4*)(rb + 4096);
    const bf16x8 kf = __builtin_bit_cast(bf16x8, kc);
    /* two INDEPENDENT S chains (q-sub 0 and 1) — interleaved by scheduler */
    f32x16 S0 = MFMA32(kf, qf0, fzero16(), 0, 0, 0);
    f32x16 S1 = MFMA32(kf, qf1, fzero16(), 0, 0, 0);
    float ts0 = 0.f, ts1 = 0.f;
#pragma unroll
    for (int r = 0; r < 16; ++r) { S0[r] = __builtin_amdgcn_exp2f(S0[r]); ts0 += S0[r]; }
#pragma unroll
    for (int r = 0; r < 16; ++r) { S1[r] = __builtin_amdgcn_exp2f(S1[r]); ts1 += S1[r]; }
    l0 += ts0; l1 += ts1;
    bf16x8 pa0, pa1, pc0, pc1;
#pragma unroll
    for (int r = 0; r < 8; ++r) {
      pa0[r] = (bf16)S0[r]; pa1[r] = (bf16)S0[r + 8];
      pc0[r] = (bf16)S1[r]; pc1[r] = (bf16)S1[r + 8];
    }
    /* PV: 8 MFMAs; V fragments shared by both q-subtiles */
    O00 = MFMA32(__builtin_bit_cast(bf16x8, v0), pa0, O00, 0, 0, 0);
    O10 = MFMA32(__builtin_bit_cast(bf16x8, v0), pc0, O10, 0, 0, 0);
    O01 = MFMA32(__builtin_bit_cast(bf16x8, v1), pa0, O01, 0, 0, 0);
    O11 = MFMA32(__builtin_bit_cast(bf16x8, v1), pc0, O11, 0, 0, 0);
    O00 = MFMA32(__builtin_bit_cast(bf16x8, v2), pa1, O00, 0, 0, 0);
    O10 = MFMA32(__builtin_bit_cast(bf16x8, v2), pc1, O10, 0, 0, 0);
    O01 = MFMA32(__builtin_bit_cast(bf16x8, v3), pa1, O01, 0, 0, 0);
    O11 = MFMA32(__builtin_bit_cast(bf16x8, v3), pc1, O11, 0, 0, 0);
    /* ds_reads of this slot fully retired before the DMA may overwrite it */
    asm volatile("s_waitcnt lgkmcnt(0)" ::: "memory");
    if (it + 2 < 32) {
      char* dst = ring + (it & 1) * 5120;
      const char* ks = kdma + (size_t)(it + 2) * 1024;
      const char* vs = vdma + (size_t)(it + 2) * 4096;
      dma16(ks, dst);
      dma16(vs, dst + 1024);
      dma16(vs + 1024, dst + 2048);
      dma16(vs + 2048, dst + 3072);
      dma16(vs + 3072, dst + 4096);
    }
  }
  l0 += __shfl_xor(l0, 32, 64);
  l1 += __shfl_xor(l1, 32, 64);

  __syncthreads();   /* ring traffic done block-wide; reuse LDS for combine */

  /* partials: slice s = wid*2 + qsub; Opart[s][n 32][16 x 8B chunks] swizzled */
  {
    const int msk = 2 * (ln & 7);
#pragma unroll
    for (int hq = 0; hq < 2; ++hq) {
      char* orow = smem + (wid * 2 + hq) * 4096 + ln * 128;
#pragma unroll
      for (int hc = 0; hc < 2; ++hc) {
        const f32x16& O = hq ? (hc ? O11 : O10) : (hc ? O01 : O00);
#pragma unroll
        for (int j = 0; j < 4; ++j) {
          bf16x4 e;
#pragma unroll
          for (int i = 0; i < 4; ++i) e[i] = (bf16)O[4 * j + i];
          const int chunk = hc * 8 + 2 * j + g;
          *(bf16x4*)(orow + ((chunk ^ msk) << 3)) = e;
        }
      }
      if (g == 0) *(float*)(smem + 32768 + (wid * 2 + hq) * 128 + ln * 4) = hq ? l1 : l0;
    }
  }
  __syncthreads();

  /* combine 4 key-range partials per q-subtile -> xc[:,0:64] */
  {
    const int n = t >> 3, k8 = t & 7;
    const int off = ((2 * k8) ^ (2 * (n & 7))) << 3;
#pragma unroll
    for (int hq = 0; hq < 2; ++hq) {
      float L = 0.f;
      float acc[8];
#pragma unroll
      for (int e = 0; e < 8; ++e) acc[e] = 0.f;
#pragma unroll
      for (int kr_ = 0; kr_ < 4; ++kr_) {
        const int s = kr_ * 2 + hq;
        L += *(const float*)(smem + 32768 + s * 128 + n * 4);
        const bf16x8 v = *(const bf16x8*)(smem + s * 4096 + n * 128 + off);
#pragma unroll
        for (int e = 0; e < 8; ++e) acc[e] += (float)v[e];
      }
      const float rL = 1.0f / L;
      bf16x8 o8;
#pragma unroll
      for (int e = 0; e < 8; ++e) o8[e] = (bf16)fmaxf(acc[e] * rL, 0.f);
      *(bf16x8*)(xc + ((size_t)b * 4096 + qblk * 64 + hq * 32 + n) * 256 + k8 * 8) = o8;
    }
  }
  __syncthreads();

  /* fused prep_x2: relu(x2) -> bf16 transpose into xc[n][64:256] (64 rows) */
  {
    unsigned* tile_u = (unsigned*)smem;  /* [64 n][97 stride] words */
    const float* xb = x + ((size_t)b * 256 + 64) * 4096 + qblk * 64;
#pragma unroll
    for (int i = 0; i < 6; ++i) {
      const int idx = i * 256 + t;
      const int cp = idx >> 4, f = idx & 15;
      const float4 a = *(const float4*)(xb + (size_t)(2 * cp) * 4096 + f * 4);
      const float4 c4 = *(const float4*)(xb + (size_t)(2 * cp + 1) * 4096 + f * 4);
      const float av[4] = {a.x, a.y, a.z, a.w};
      const float cv[4] = {c4.x, c4.y, c4.z, c4.w};
#pragma unroll
      for (int e = 0; e < 4; ++e) {
        const unsigned u =
            (unsigned)__builtin_bit_cast(unsigned short, (bf16)fmaxf(av[e], 0.f)) |
            ((unsigned)__builtin_bit_cast(unsigned short, (bf16)fmaxf(cv[e], 0.f)) << 16);
        tile_u[(f * 4 + e) * 97 + cp] = u;
      }
    }
    __syncthreads();
#pragma unroll
    for (int i = 0; i < 6; ++i) {
      const int idx = i * 256 + t;
      const int n = idx / 24, q = idx % 24;
      const uint4 d = *(const uint4*)&tile_u[n * 97 + q * 4];
      *(uint4*)(xc + ((size_t)b * 4096 + qblk * 64 + n) * 256 + 64 + q * 8) = d;
    }
  }
}

/* ---------- kernel 4: proj matmul (MFMA bf16) + BN, 128n x 128o tile ---------- */
__global__ __launch_bounds__(256, 2) void k_proj(
    const bf16* __restrict__ xc, const float* __restrict__ pw,
    const float* __restrict__ bn_g, const float* __restrict__ bn_b,
    const float* __restrict__ bn_rm, const float* __restrict__ bn_rv,
    float* __restrict__ out) {
  const int orig = blockIdx.x;
  const int wg = (orig & 7) * 64 + (orig >> 3);  /* XCD swizzle, 512 blocks */
  const int b = wg >> 6, rem = wg & 63, nt = rem >> 1, oh = rem & 1;
  const int n0 = nt * 128, o0 = oh * 128;
  const int t = threadIdx.x, w = t >> 6, l = t & 63, ln = l & 31, g = l >> 5;

  __shared__ __align__(16) bf16 pws[128 * 256];
  __shared__ float beta_s[128];

  {
    const int o = t >> 1, half = t & 1;
    const float inv = bn_g[o0 + o] * rsqrtf(bn_rv[o0 + o] + EPSV);
    if (half == 0) beta_s[o] = bn_b[o0 + o] - bn_rm[o0 + o] * inv;
    const float* wr = pw + (size_t)(o0 + o) * 256 + half * 128;
    const int s_hh = (o & 15) * 8;
#pragma unroll
    for (int j = 0; j < 16; ++j) {
      const float4 a = ((const float4*)wr)[j * 2];
      const float4 c4 = ((const float4*)wr)[j * 2 + 1];
      bf16x8 v8;
      v8[0] = (bf16)(a.x * inv);  v8[1] = (bf16)(a.y * inv);
      v8[2] = (bf16)(a.z * inv);  v8[3] = (bf16)(a.w * inv);
      v8[4] = (bf16)(c4.x * inv); v8[5] = (bf16)(c4.y * inv);
      v8[6] = (bf16)(c4.z * inv); v8[7] = (bf16)(c4.w * inv);
      *(bf16x8*)&pws[o * 256 + ((half * 128 + j * 8) ^ s_hh)] = v8;
    }
  }
  __syncthreads();

  const bf16* xrow = xc + ((size_t)b * 4096 + n0 + w * 32 + ln) * 256;
  const int sw = (ln & 15) * 8;
  f32x16 acc0 = fzero16(), acc1 = fzero16(), acc2 = fzero16(), acc3 = fzero16();
#pragma unroll 4
  for (int ck = 0; ck < 256; ck += 16) {
    const bf16x8 bfrag = *(const bf16x8*)(xrow + ck + g * 8);
    const int cidx = (ck + g * 8) ^ sw;
    const bf16x8 a0 = *(const bf16x8*)&pws[(ln) * 256 + cidx];
    const bf16x8 a1 = *(const bf16x8*)&pws[(32 + ln) * 256 + cidx];
    const bf16x8 a2 = *(const bf16x8*)&pws[(64 + ln) * 256 + cidx];
    const bf16x8 a3 = *(const bf16x8*)&pws[(96 + ln) * 256 + cidx];
    acc0 = MFMA32(a0, bfrag, acc0, 0, 0, 0);
    acc1 = MFMA32(a1, bfrag, acc1, 0, 0, 0);
    acc2 = MFMA32(a2, bfrag, acc2, 0, 0, 0);
    acc3 = MFMA32(a3, bfrag, acc3, 0, 0, 0);
  }
  const int ncol = n0 + w * 32 + ln;
  float* ob = out + (size_t)b * 256 * 4096 + ncol;
#pragma unroll
  for (int og = 0; og < 4; ++og) {
    const f32x16& A = og == 0 ? acc0 : og == 1 ? acc1 : og == 2 ? acc2 : acc3;
#pragma unroll
    for (int r = 0; r < 16; ++r) {
      const int o_loc = og * 32 + (r & 3) + 8 * (r >> 2) + 4 * g;
      ob[(size_t)(o0 + o_loc) * 4096] = A[r] + beta_s[o_loc];
    }
  }
}

/* ---------------- host launcher ---------------- */
extern "C" void kernel_launch(void* const* d_in, const int* in_sizes, int n_in,
                              void* d_out, int out_size, void* d_ws, size_t ws_size,
                              hipStream_t stream) {
  (void)in_sizes; (void)n_in; (void)out_size; (void)ws_size;
  const float* x        = (const float*)d_in[0];
  const float* gn_g     = (const float*)d_in[1];
  const float* gn_b     = (const float*)d_in[2];
  const float* qkv_w    = (const float*)d_in[3];
  const float* qkv_bn_g = (const float*)d_in[4];
  const float* qkv_bn_b = (const float*)d_in[5];
  const float* qkv_rm   = (const float*)d_in[6];
  const float* qkv_rv   = (const float*)d_in[7];
  const float* proj_w   = (const float*)d_in[8];
  const float* proj_bn_g = (const float*)d_in[9];
  const float* proj_bn_b = (const float*)d_in[10];
  const float* proj_rm  = (const float*)d_in[11];
  const float* proj_rv  = (const float*)d_in[12];

  char* ws = (char*)d_ws;
  float* part  = (float*)ws;
  float* stats = (float*)(ws + 4096);
  bf16* qw = (bf16*)(ws + 8192);
  bf16* kw = (bf16*)(ws + 8192 + (1u << 20));
  bf16* vw = (bf16*)(ws + 8192 + (2u << 20));
  bf16* xc = (bf16*)(ws + 8192 + (6u << 20));

  k_stats_partial<<<256, 256, 0, stream>>>(x, part);
  k_stats_final<<<1, 256, 0, stream>>>(part, stats);
  k_qkv<<<512, 256, 0, stream>>>(x, gn_g, gn_b, qkv_w, qkv_bn_g, qkv_bn_b,
                                 qkv_rm, qkv_rv, stats, qw, kw, vw);
  k_attn<<<512, 256, 0, stream>>>(qw, kw, vw, x, xc);
  k_proj<<<512, 256, 0, stream>>>(xc, proj_w, proj_bn_g, proj_bn_b,
                                  proj_rm, proj_rv, (float*)d_out);
}

// Round 16
// 85.970 us; speedup vs baseline: 1.0530x; 1.0176x over previous
//
#include <hip/hip_runtime.h>
#include <hip/hip_bf16.h>

typedef __bf16 bf16;
typedef __bf16 bf16x4 __attribute__((ext_vector_type(4)));
typedef __bf16 bf16x8 __attribute__((ext_vector_type(8)));
typedef float  f32x16 __attribute__((ext_vector_type(16)));

#define MFMA32 __builtin_amdgcn_mfma_f32_32x32x16_bf16
#define EPSV 1e-5f
#define QSCALE 0.36067376022224085f  /* 0.25 * log2(e) */

__device__ __forceinline__ f32x16 fzero16() {
  f32x16 z;
#pragma unroll
  for (int i = 0; i < 16; ++i) z[i] = 0.f;
  return z;
}

/* async 16B/lane global->LDS DMA (m97 pattern) */
__device__ __forceinline__ void dma16(const void* g, void* s) {
  __builtin_amdgcn_global_load_lds(
      (const __attribute__((address_space(1))) void*)g,
      (__attribute__((address_space(3))) void*)s, 16, 0, 0);
}

/* ---------------- kernel 1a: per-batch partial sums over x1 ---------------- */
__global__ __launch_bounds__(256) void k_stats_partial(const float* __restrict__ x,
                                                       float* __restrict__ part) {
  const int b = blockIdx.x >> 5, k = blockIdx.x & 31;
  const float* p = x + (size_t)b * 256 * 4096 + k * 8192;
  const int t = threadIdx.x;
  float s = 0.f, q = 0.f;
#pragma unroll
  for (int j = 0; j < 8; ++j) {
    float4 v = ((const float4*)p)[t + j * 256];
    s += v.x + v.y + v.z + v.w;
    q += v.x * v.x + v.y * v.y + v.z * v.z + v.w * v.w;
  }
  __shared__ float ls[256], lq[256];
  ls[t] = s; lq[t] = q;
  __syncthreads();
  for (int off = 128; off > 0; off >>= 1) {
    if (t < off) { ls[t] += ls[t + off]; lq[t] += lq[t + off]; }
    __syncthreads();
  }
  if (t == 0) { part[blockIdx.x * 2] = ls[0]; part[blockIdx.x * 2 + 1] = lq[0]; }
}

/* ---------------- kernel 1b: finalize mu / rstd per batch ---------------- */
__global__ __launch_bounds__(256) void k_stats_final(const float* __restrict__ part,
                                                     float* __restrict__ stats) {
  const int t = threadIdx.x, b = t >> 5, k = t & 31;
  float s = part[(b * 32 + k) * 2], q = part[(b * 32 + k) * 2 + 1];
  for (int off = 16; off > 0; off >>= 1) {
    s += __shfl_down(s, off, 32);
    q += __shfl_down(q, off, 32);
  }
  if (k == 0) {
    const float inv_n = 1.f / 262144.f;
    const float mu = s * inv_n;
    const float var = q * inv_n - mu * mu;
    stats[b * 2] = mu;
    stats[b * 2 + 1] = rsqrtf(var + EPSV);
  }
}

/* ------- kernel 2: GN-normalize x1, qkv matmul + BN, emit q/k/v bf16 -------
   V written in MFMA-FRAGMENT-MAJOR layout (see R8 comment).                 */
__global__ __launch_bounds__(256) void k_qkv(
    const float* __restrict__ x, const float* __restrict__ gn_g, const float* __restrict__ gn_b,
    const float* __restrict__ qkv_w, const float* __restrict__ bn_g, const float* __restrict__ bn_b,
    const float* __restrict__ bn_rm, const float* __restrict__ bn_rv,
    const float* __restrict__ stats,
    bf16* __restrict__ qw, bf16* __restrict__ kw, bf16* __restrict__ vw) {
  const int b = blockIdx.x >> 6, tile = blockIdx.x & 63;
  const int n0 = tile * 64, t = threadIdx.x;
  __shared__ float xn[64][68];
  __shared__ float W[64][96];
  __shared__ float beta_s[96];
  const float mu = stats[b * 2], rstd = stats[b * 2 + 1];
  {
    const int c = t >> 2, f = t & 3;
    const float A = rstd * gn_g[c], B = gn_b[c] - mu * A;
    const float* xr = x + ((size_t)b * 256 + c) * 4096 + n0;
#pragma unroll
    for (int j = 0; j < 4; ++j) {
      float4 v = ((const float4*)xr)[f * 4 + j];
      const int nb = f * 16 + j * 4;
      xn[c][nb + 0] = v.x * A + B; xn[c][nb + 1] = v.y * A + B;
      xn[c][nb + 2] = v.z * A + B; xn[c][nb + 3] = v.w * A + B;
    }
  }
  for (int oc = t; oc < 96 * 8; oc += 256) {
    const int o = oc >> 3, ch = (oc & 7) * 8;
    const float inv = bn_g[o] * rsqrtf(bn_rv[o] + EPSV);
    if (ch == 0) beta_s[o] = bn_b[o] - bn_rm[o] * inv;
    const float* wr = qkv_w + o * 64 + ch;
#pragma unroll
    for (int i = 0; i < 8; ++i) W[ch + i][o] = wr[i] * inv;
  }
  __syncthreads();
  const int o_l = t & 31, ng = t >> 5;
#pragma unroll 1
  for (int p = 0; p < 3; ++p) {
    const int o = p * 32 + o_l;
    float acc[8];
#pragma unroll
    for (int j = 0; j < 8; ++j) acc[j] = 0.f;
    for (int c = 0; c < 64; ++c) {
      const float wv = W[c][o];
      const float* xr = &xn[c][ng * 8];
#pragma unroll
      for (int j = 0; j < 8; ++j) acc[j] += wv * xr[j];
    }
    const float beta = beta_s[o];
    const int nb = n0 + ng * 8;
    if (p == 0) {
      if (o < 16) {
#pragma unroll
        for (int j = 0; j < 8; ++j)
          qw[((size_t)b * 4096 + nb + j) * 16 + o] = (bf16)((acc[j] + beta) * QSCALE);
      } else {
#pragma unroll
        for (int j = 0; j < 8; ++j)
          kw[((size_t)b * 4096 + nb + j) * 16 + (o - 16)] = (bf16)(acc[j] + beta);
      }
    } else {
      const int c = (p - 1) * 32 + o_l;
      const int IT = nb >> 5;
      const int m4 = nb & 31;
      const int f  = ((m4 >> 4) << 1) + (c >> 5);
      const int b3 = (m4 >> 3) & 1;
      char* base = (char*)vw + (size_t)b * 524288 + (size_t)IT * 4096 +
                   f * 1024 + (c & 31) * 16 + b3 * 8;
      bf16x4 pk0, pk1;
#pragma unroll
      for (int i = 0; i < 4; ++i) {
        pk0[i] = (bf16)(acc[i] + beta);
        pk1[i] = (bf16)(acc[4 + i] + beta);
      }
      *(bf16x4*)base = pk0;
      *(bf16x4*)(base + 512) = pk1;
    }
  }
}

/* ------- kernel 3: flash attention, 3-deep async-DMA ring, 64 q/wave --------
   grid 512 (XCD-swizzled, batch-per-XCD); 256 thr = 4 waves = 4 key-ranges
   of 1024 keys, all for the SAME 64 queries. Ring R=3 slots/wave, DMA issued
   3 tiles ahead RIGHT AFTER this slot's ds_reads retire (cover ~3 bodies vs
   R15's ~1 — the last latency lever). Counted vmcnt(10). Tree-summed l.
   End: in-LDS 8-slice split-K combine + fused relu(x2) transpose.            */
__global__ __launch_bounds__(256, 2) void k_attn(
    const bf16* __restrict__ qw, const bf16* __restrict__ kw,
    const bf16* __restrict__ vw, const float* __restrict__ x,
    bf16* __restrict__ xc) {
  __shared__ __align__(16) char smem[61440];   /* 4 waves x 3 slots x 5KB */
  const int orig = blockIdx.x;
  const int wg = (orig & 7) * 64 + (orig >> 3);  /* XCD j <- batch j */
  const int b = wg >> 6, qblk = wg & 63;
  const int t = threadIdx.x;
  const int wid = t >> 6, l = t & 63, ln = l & 31, g = l >> 5;
  const int m0 = wid * 1024;

  const bf16* qb = qw + (size_t)b * 4096 * 16;
  const char* kb = (const char*)(kw + (size_t)b * 4096 * 16);
  const char* vfb = (const char*)vw + (size_t)b * 524288;

  const char* kdma = kb + (size_t)m0 * 32 + (2 * ln + g) * 16;
  const char* vdma = vfb + (size_t)(m0 >> 5) * 4096 + l * 16;
  char* ring = smem + wid * 15360;

  const int nq = qblk * 64 + ln;
  const bf16x8 qf0 = *(const bf16x8*)(qb + (size_t)nq * 16 + g * 8);
  const bf16x8 qf1 = *(const bf16x8*)(qb + (size_t)(nq + 32) * 16 + g * 8);
  asm volatile("" :: "v"(qf0), "v"(qf1));

  f32x16 O00 = fzero16(), O01 = fzero16();
  f32x16 O10 = fzero16(), O11 = fzero16();
  float l0 = 0.f, l1 = 0.f;

#define ISSUE_TILE(TI, SLOT)                                  \
  do {                                                        \
    char* dst = ring + (SLOT) * 5120;                         \
    const char* ks = kdma + (size_t)(TI) * 1024;              \
    const char* vs = vdma + (size_t)(TI) * 4096;              \
    dma16(ks, dst);                                           \
    dma16(vs, dst + 1024);                                    \
    dma16(vs + 1024, dst + 2048);                             \
    dma16(vs + 2048, dst + 3072);                             \
    dma16(vs + 3072, dst + 4096);                             \
  } while (0)

  /* prologue: tiles 0,1,2 in flight (15 outstanding) */
  ISSUE_TILE(0, 0);
  ISSUE_TILE(1, 1);
  ISSUE_TILE(2, 2);

  int slot = 0;
#pragma unroll 1
  for (int it = 0; it < 32; ++it) {
    const int rem = 31 - it;   /* tiles still outstanding beyond this one */
    if (rem >= 2)      { asm volatile("s_waitcnt vmcnt(10)" ::: "memory"); }
    else if (rem == 1) { asm volatile("s_waitcnt vmcnt(5)"  ::: "memory"); }
    else               { asm volatile("s_waitcnt vmcnt(0)"  ::: "memory"); }
    const char* rb = ring + slot * 5120 + l * 16;
    const uint4 kc = *(const uint4*)rb;
    const uint4 v0 = *(const uint4*)(rb + 1024);
    const uint4 v1 = *(const uint4*)(rb + 2048);
    const uint4 v2 = *(const uint4*)(rb + 3072);
    const uint4 v3 = *(const uint4*)(rb + 4096);
    /* ds_reads retired -> slot reusable; refill 3 ahead BEFORE compute */
    asm volatile("s_waitcnt lgkmcnt(0)" ::: "memory");
    if (it + 3 < 32) ISSUE_TILE(it + 3, slot);
    const bf16x8 kf = __builtin_bit_cast(bf16x8, kc);
    /* two independent S chains */
    f32x16 S0 = MFMA32(kf, qf0, fzero16(), 0, 0, 0);
    f32x16 S1 = MFMA32(kf, qf1, fzero16(), 0, 0, 0);
#pragma unroll
    for (int r = 0; r < 16; ++r) S0[r] = __builtin_amdgcn_exp2f(S0[r]);
#pragma unroll
    for (int r = 0; r < 16; ++r) S1[r] = __builtin_amdgcn_exp2f(S1[r]);
    {  /* tree-sum (depth 4) */
      float a[8], c[8];
#pragma unroll
      for (int r = 0; r < 8; ++r) { a[r] = S0[2 * r] + S0[2 * r + 1];
                                    c[r] = S1[2 * r] + S1[2 * r + 1]; }
#pragma unroll
      for (int r = 0; r < 4; ++r) { a[r] = a[2 * r] + a[2 * r + 1];
                                    c[r] = c[2 * r] + c[2 * r + 1]; }
      l0 += (a[0] + a[1]) + (a[2] + a[3]);
      l1 += (c[0] + c[1]) + (c[2] + c[3]);
    }
    bf16x8 pa0, pa1, pc0, pc1;
#pragma unroll
    for (int r = 0; r < 8; ++r) {
      pa0[r] = (bf16)S0[r]; pa1[r] = (bf16)S0[r + 8];
      pc0[r] = (bf16)S1[r]; pc1[r] = (bf16)S1[r + 8];
    }
    O00 = MFMA32(__builtin_bit_cast(bf16x8, v0), pa0, O00, 0, 0, 0);
    O10 = MFMA32(__builtin_bit_cast(bf16x8, v0), pc0, O10, 0, 0, 0);
    O01 = MFMA32(__builtin_bit_cast(bf16x8, v1), pa0, O01, 0, 0, 0);
    O11 = MFMA32(__builtin_bit_cast(bf16x8, v1), pc0, O11, 0, 0, 0);
    O00 = MFMA32(__builtin_bit_cast(bf16x8, v2), pa1, O00, 0, 0, 0);
    O10 = MFMA32(__builtin_bit_cast(bf16x8, v2), pc1, O10, 0, 0, 0);
    O01 = MFMA32(__builtin_bit_cast(bf16x8, v3), pa1, O01, 0, 0, 0);
    O11 = MFMA32(__builtin_bit_cast(bf16x8, v3), pc1, O11, 0, 0, 0);
    slot = (slot == 2) ? 0 : slot + 1;
  }
#undef ISSUE_TILE
  l0 += __shfl_xor(l0, 32, 64);
  l1 += __shfl_xor(l1, 32, 64);

  __syncthreads();

  /* partials: slice s = wid*2 + qsub; Opart[s][n 32][16 x 8B chunks] swizzled */
  {
    const int msk = 2 * (ln & 7);
#pragma unroll
    for (int hq = 0; hq < 2; ++hq) {
      char* orow = smem + (wid * 2 + hq) * 4096 + ln * 128;
#pragma unroll
      for (int hc = 0; hc < 2; ++hc) {
        const f32x16& O = hq ? (hc ? O11 : O10) : (hc ? O01 : O00);
#pragma unroll
        for (int j = 0; j < 4; ++j) {
          bf16x4 e;
#pragma unroll
          for (int i = 0; i < 4; ++i) e[i] = (bf16)O[4 * j + i];
          const int chunk = hc * 8 + 2 * j + g;
          *(bf16x4*)(orow + ((chunk ^ msk) << 3)) = e;
        }
      }
      if (g == 0) *(float*)(smem + 32768 + (wid * 2 + hq) * 128 + ln * 4) = hq ? l1 : l0;
    }
  }
  __syncthreads();

  /* combine 4 key-range partials per q-subtile -> xc[:,0:64] */
  {
    const int n = t >> 3, k8 = t & 7;
    const int off = ((2 * k8) ^ (2 * (n & 7))) << 3;
#pragma unroll
    for (int hq = 0; hq < 2; ++hq) {
      float L = 0.f;
      float acc[8];
#pragma unroll
      for (int e = 0; e < 8; ++e) acc[e] = 0.f;
#pragma unroll
      for (int kr_ = 0; kr_ < 4; ++kr_) {
        const int s = kr_ * 2 + hq;
        L += *(const float*)(smem + 32768 + s * 128 + n * 4);
        const bf16x8 v = *(const bf16x8*)(smem + s * 4096 + n * 128 + off);
#pragma unroll
        for (int e = 0; e < 8; ++e) acc[e] += (float)v[e];
      }
      const float rL = 1.0f / L;
      bf16x8 o8;
#pragma unroll
      for (int e = 0; e < 8; ++e) o8[e] = (bf16)fmaxf(acc[e] * rL, 0.f);
      *(bf16x8*)(xc + ((size_t)b * 4096 + qblk * 64 + hq * 32 + n) * 256 + k8 * 8) = o8;
    }
  }
  __syncthreads();

  /* fused prep_x2: relu(x2) -> bf16 transpose into xc[n][64:256] (64 rows) */
  {
    unsigned* tile_u = (unsigned*)smem;  /* [64 n][97 stride] words */
    const float* xb = x + ((size_t)b * 256 + 64) * 4096 + qblk * 64;
#pragma unroll
    for (int i = 0; i < 6; ++i) {
      const int idx = i * 256 + t;
      const int cp = idx >> 4, f = idx & 15;
      const float4 a = *(const float4*)(xb + (size_t)(2 * cp) * 4096 + f * 4);
      const float4 c4 = *(const float4*)(xb + (size_t)(2 * cp + 1) * 4096 + f * 4);
      const float av[4] = {a.x, a.y, a.z, a.w};
      const float cv[4] = {c4.x, c4.y, c4.z, c4.w};
#pragma unroll
      for (int e = 0; e < 4; ++e) {
        const unsigned u =
            (unsigned)__builtin_bit_cast(unsigned short, (bf16)fmaxf(av[e], 0.f)) |
            ((unsigned)__builtin_bit_cast(unsigned short, (bf16)fmaxf(cv[e], 0.f)) << 16);
        tile_u[(f * 4 + e) * 97 + cp] = u;
      }
    }
    __syncthreads();
#pragma unroll
    for (int i = 0; i < 6; ++i) {
      const int idx = i * 256 + t;
      const int n = idx / 24, q = idx % 24;
      const uint4 d = *(const uint4*)&tile_u[n * 97 + q * 4];
      *(uint4*)(xc + ((size_t)b * 4096 + qblk * 64 + n) * 256 + 64 + q * 8) = d;
    }
  }
}

/* ---------- kernel 4: proj matmul (MFMA bf16) + BN, 128n x 128o tile ---------- */
__global__ __launch_bounds__(256, 2) void k_proj(
    const bf16* __restrict__ xc, const float* __restrict__ pw,
    const float* __restrict__ bn_g, const float* __restrict__ bn_b,
    const float* __restrict__ bn_rm, const float* __restrict__ bn_rv,
    float* __restrict__ out) {
  const int orig = blockIdx.x;
  const int wg = (orig & 7) * 64 + (orig >> 3);
  const int b = wg >> 6, rem = wg & 63, nt = rem >> 1, oh = rem & 1;
  const int n0 = nt * 128, o0 = oh * 128;
  const int t = threadIdx.x, w = t >> 6, l = t & 63, ln = l & 31, g = l >> 5;

  __shared__ __align__(16) bf16 pws[128 * 256];
  __shared__ float beta_s[128];

  {
    const int o = t >> 1, half = t & 1;
    const float inv = bn_g[o0 + o] * rsqrtf(bn_rv[o0 + o] + EPSV);
    if (half == 0) beta_s[o] = bn_b[o0 + o] - bn_rm[o0 + o] * inv;
    const float* wr = pw + (size_t)(o0 + o) * 256 + half * 128;
    const int s_hh = (o & 15) * 8;
#pragma unroll
    for (int j = 0; j < 16; ++j) {
      const float4 a = ((const float4*)wr)[j * 2];
      const float4 c4 = ((const float4*)wr)[j * 2 + 1];
      bf16x8 v8;
      v8[0] = (bf16)(a.x * inv);  v8[1] = (bf16)(a.y * inv);
      v8[2] = (bf16)(a.z * inv);  v8[3] = (bf16)(a.w * inv);
      v8[4] = (bf16)(c4.x * inv); v8[5] = (bf16)(c4.y * inv);
      v8[6] = (bf16)(c4.z * inv); v8[7] = (bf16)(c4.w * inv);
      *(bf16x8*)&pws[o * 256 + ((half * 128 + j * 8) ^ s_hh)] = v8;
    }
  }
  __syncthreads();

  const bf16* xrow = xc + ((size_t)b * 4096 + n0 + w * 32 + ln) * 256;
  const int sw = (ln & 15) * 8;
  f32x16 acc0 = fzero16(), acc1 = fzero16(), acc2 = fzero16(), acc3 = fzero16();
#pragma unroll 4
  for (int ck = 0; ck < 256; ck += 16) {
    const bf16x8 bfrag = *(const bf16x8*)(xrow + ck + g * 8);
    const int cidx = (ck + g * 8) ^ sw;
    const bf16x8 a0 = *(const bf16x8*)&pws[(ln) * 256 + cidx];
    const bf16x8 a1 = *(const bf16x8*)&pws[(32 + ln) * 256 + cidx];
    const bf16x8 a2 = *(const bf16x8*)&pws[(64 + ln) * 256 + cidx];
    const bf16x8 a3 = *(const bf16x8*)&pws[(96 + ln) * 256 + cidx];
    acc0 = MFMA32(a0, bfrag, acc0, 0, 0, 0);
    acc1 = MFMA32(a1, bfrag, acc1, 0, 0, 0);
    acc2 = MFMA32(a2, bfrag, acc2, 0, 0, 0);
    acc3 = MFMA32(a3, bfrag, acc3, 0, 0, 0);
  }
  const int ncol = n0 + w * 32 + ln;
  float* ob = out + (size_t)b * 256 * 4096 + ncol;
#pragma unroll
  for (int og = 0; og < 4; ++og) {
    const f32x16& A = og == 0 ? acc0 : og == 1 ? acc1 : og == 2 ? acc2 : acc3;
#pragma unroll
    for (int r = 0; r < 16; ++r) {
      const int o_loc = og * 32 + (r & 3) + 8 * (r >> 2) + 4 * g;
      ob[(size_t)(o0 + o_loc) * 4096] = A[r] + beta_s[o_loc];
    }
  }
}

/* ---------------- host launcher ---------------- */
extern "C" void kernel_launch(void* const* d_in, const int* in_sizes, int n_in,
                              void* d_out, int out_size, void* d_ws, size_t ws_size,
                              hipStream_t stream) {
  (void)in_sizes; (void)n_in; (void)out_size; (void)ws_size;
  const float* x        = (const float*)d_in[0];
  const float* gn_g     = (const float*)d_in[1];
  const float* gn_b     = (const float*)d_in[2];
  const float* qkv_w    = (const float*)d_in[3];
  const float* qkv_bn_g = (const float*)d_in[4];
  const float* qkv_bn_b = (const float*)d_in[5];
  const float* qkv_rm   = (const float*)d_in[6];
  const float* qkv_rv   = (const float*)d_in[7];
  const float* proj_w   = (const float*)d_in[8];
  const float* proj_bn_g = (const float*)d_in[9];
  const float* proj_bn_b = (const float*)d_in[10];
  const float* proj_rm  = (const float*)d_in[11];
  const float* proj_rv  = (const float*)d_in[12];

  char* ws = (char*)d_ws;
  float* part  = (float*)ws;
  float* stats = (float*)(ws + 4096);
  bf16* qw = (bf16*)(ws + 8192);
  bf16* kw = (bf16*)(ws + 8192 + (1u << 20));
  bf16* vw = (bf16*)(ws + 8192 + (2u << 20));
  bf16* xc = (bf16*)(ws + 8192 + (6u << 20));

  k_stats_partial<<<256, 256, 0, stream>>>(x, part);
  k_stats_final<<<1, 256, 0, stream>>>(part, stats);
  k_qkv<<<512, 256, 0, stream>>>(x, gn_g, gn_b, qkv_w, qkv_bn_g, qkv_bn_b,
                                 qkv_rm, qkv_rv, stats, qw, kw, vw);
  k_attn<<<512, 256, 0, stream>>>(qw, kw, vw, x, xc);
  k_proj<<<512, 256, 0, stream>>>(xc, proj_w, proj_bn_g, proj_bn_b,
                                  proj_rm, proj_rv, (float*)d_out);
}

// Round 17
// 81.056 us; speedup vs baseline: 1.1169x; 1.0606x over previous
//
#include <hip/hip_runtime.h>
#include <hip/hip_bf16.h>

typedef __bf16 bf16;
typedef __bf16 bf16x4 __attribute__((ext_vector_type(4)));
typedef __bf16 bf16x8 __attribute__((ext_vector_type(8)));
typedef float  f32x16 __attribute__((ext_vector_type(16)));

#define MFMA32 __builtin_amdgcn_mfma_f32_32x32x16_bf16
#define EPSV 1e-5f
#define QSCALE 0.36067376022224085f  /* 0.25 * log2(e) */

__device__ __forceinline__ f32x16 fzero16() {
  f32x16 z;
#pragma unroll
  for (int i = 0; i < 16; ++i) z[i] = 0.f;
  return z;
}

/* async 16B/lane global->LDS DMA (m97 pattern) */
__device__ __forceinline__ void dma16(const void* g, void* s) {
  __builtin_amdgcn_global_load_lds(
      (const __attribute__((address_space(1))) void*)g,
      (__attribute__((address_space(3))) void*)s, 16, 0, 0);
}

/* ---- kernel 1a: per-batch partial sums over x1 (+64 pw-convert blocks) ---- */
__global__ __launch_bounds__(256) void k_stats_partial(
    const float* __restrict__ x, const float* __restrict__ pw,
    const float* __restrict__ pg, const float* __restrict__ prv,
    const float* __restrict__ prm, const float* __restrict__ pbb,
    float* __restrict__ part, bf16* __restrict__ pwb, float* __restrict__ pwbeta) {
  if (blockIdx.x >= 256) {       /* pw': bf16(pw*inv), beta */
    const int pb = blockIdx.x - 256;
    const int t = threadIdx.x;
    const int o = pb * 4 + (t >> 6), cseg = (t & 63) * 4;
    const float inv = pg[o] * rsqrtf(prv[o] + EPSV);
    const float4 v = *(const float4*)(pw + (size_t)o * 256 + cseg);
    bf16x4 pk;
    pk[0] = (bf16)(v.x * inv); pk[1] = (bf16)(v.y * inv);
    pk[2] = (bf16)(v.z * inv); pk[3] = (bf16)(v.w * inv);
    *(bf16x4*)(pwb + (size_t)o * 256 + cseg) = pk;
    if ((t & 63) == 0) pwbeta[o] = pbb[o] - prm[o] * inv;
    return;
  }
  const int b = blockIdx.x >> 5, k = blockIdx.x & 31;
  const float* p = x + (size_t)b * 256 * 4096 + k * 8192;
  const int t = threadIdx.x;
  float s = 0.f, q = 0.f;
#pragma unroll
  for (int j = 0; j < 8; ++j) {
    float4 v = ((const float4*)p)[t + j * 256];
    s += v.x + v.y + v.z + v.w;
    q += v.x * v.x + v.y * v.y + v.z * v.z + v.w * v.w;
  }
  __shared__ float ls[256], lq[256];
  ls[t] = s; lq[t] = q;
  __syncthreads();
  for (int off = 128; off > 0; off >>= 1) {
    if (t < off) { ls[t] += ls[t + off]; lq[t] += lq[t + off]; }
    __syncthreads();
  }
  if (t == 0) { part[blockIdx.x * 2] = ls[0]; part[blockIdx.x * 2 + 1] = lq[0]; }
}

/* ---------------- kernel 1b: finalize mu / rstd per batch ---------------- */
__global__ __launch_bounds__(256) void k_stats_final(const float* __restrict__ part,
                                                     float* __restrict__ stats) {
  const int t = threadIdx.x, b = t >> 5, k = t & 31;
  float s = part[(b * 32 + k) * 2], q = part[(b * 32 + k) * 2 + 1];
  for (int off = 16; off > 0; off >>= 1) {
    s += __shfl_down(s, off, 32);
    q += __shfl_down(q, off, 32);
  }
  if (k == 0) {
    const float inv_n = 1.f / 262144.f;
    const float mu = s * inv_n;
    const float var = q * inv_n - mu * mu;
    stats[b * 2] = mu;
    stats[b * 2 + 1] = rsqrtf(var + EPSV);
  }
}

/* ------- kernel 2: GN-normalize x1, qkv matmul + BN, emit q/k/v bf16 -------
   V written in MFMA-FRAGMENT-MAJOR layout (see R8 comment).                 */
__global__ __launch_bounds__(256) void k_qkv(
    const float* __restrict__ x, const float* __restrict__ gn_g, const float* __restrict__ gn_b,
    const float* __restrict__ qkv_w, const float* __restrict__ bn_g, const float* __restrict__ bn_b,
    const float* __restrict__ bn_rm, const float* __restrict__ bn_rv,
    const float* __restrict__ stats,
    bf16* __restrict__ qw, bf16* __restrict__ kw, bf16* __restrict__ vw) {
  const int b = blockIdx.x >> 6, tile = blockIdx.x & 63;
  const int n0 = tile * 64, t = threadIdx.x;
  __shared__ float xn[64][68];
  __shared__ float W[64][96];
  __shared__ float beta_s[96];
  const float mu = stats[b * 2], rstd = stats[b * 2 + 1];
  {
    const int c = t >> 2, f = t & 3;
    const float A = rstd * gn_g[c], B = gn_b[c] - mu * A;
    const float* xr = x + ((size_t)b * 256 + c) * 4096 + n0;
#pragma unroll
    for (int j = 0; j < 4; ++j) {
      float4 v = ((const float4*)xr)[f * 4 + j];
      const int nb = f * 16 + j * 4;
      xn[c][nb + 0] = v.x * A + B; xn[c][nb + 1] = v.y * A + B;
      xn[c][nb + 2] = v.z * A + B; xn[c][nb + 3] = v.w * A + B;
    }
  }
  for (int oc = t; oc < 96 * 8; oc += 256) {
    const int o = oc >> 3, ch = (oc & 7) * 8;
    const float inv = bn_g[o] * rsqrtf(bn_rv[o] + EPSV);
    if (ch == 0) beta_s[o] = bn_b[o] - bn_rm[o] * inv;
    const float* wr = qkv_w + o * 64 + ch;
#pragma unroll
    for (int i = 0; i < 8; ++i) W[ch + i][o] = wr[i] * inv;
  }
  __syncthreads();
  const int o_l = t & 31, ng = t >> 5;
#pragma unroll 1
  for (int p = 0; p < 3; ++p) {
    const int o = p * 32 + o_l;
    float acc[8];
#pragma unroll
    for (int j = 0; j < 8; ++j) acc[j] = 0.f;
    for (int c = 0; c < 64; ++c) {
      const float wv = W[c][o];
      const float* xr = &xn[c][ng * 8];
#pragma unroll
      for (int j = 0; j < 8; ++j) acc[j] += wv * xr[j];
    }
    const float beta = beta_s[o];
    const int nb = n0 + ng * 8;
    if (p == 0) {
      if (o < 16) {
#pragma unroll
        for (int j = 0; j < 8; ++j)
          qw[((size_t)b * 4096 + nb + j) * 16 + o] = (bf16)((acc[j] + beta) * QSCALE);
      } else {
#pragma unroll
        for (int j = 0; j < 8; ++j)
          kw[((size_t)b * 4096 + nb + j) * 16 + (o - 16)] = (bf16)(acc[j] + beta);
      }
    } else {
      const int c = (p - 1) * 32 + o_l;
      const int IT = nb >> 5;
      const int m4 = nb & 31;
      const int f  = ((m4 >> 4) << 1) + (c >> 5);
      const int b3 = (m4 >> 3) & 1;
      char* base = (char*)vw + (size_t)b * 524288 + (size_t)IT * 4096 +
                   f * 1024 + (c & 31) * 16 + b3 * 8;
      bf16x4 pk0, pk1;
#pragma unroll
      for (int i = 0; i < 4; ++i) {
        pk0[i] = (bf16)(acc[i] + beta);
        pk1[i] = (bf16)(acc[4 + i] + beta);
      }
      *(bf16x4*)base = pk0;
      *(bf16x4*)(base + 512) = pk1;
    }
  }
}

/* --- kernel 3: FUSED flash attention + prep_x2 + proj + BN -> out ---------
   grid 512 (XCD-swizzled, batch-per-XCD); 256 thr = 4 waves = 4 key-ranges
   of 1024 keys for the SAME 64 queries. Main loop = R16 verbatim (3-deep
   async-DMA ring, counted vmcnt). Epilogue: xc tile held ENTIRELY IN LDS
   (combine -> cols 0:64, relu(x2) transpose -> cols 64:256, XOR-granule
   swizzled), then proj MFMA over 4 o-chunks of pre-converted bf16 weights,
   + beta, direct coalesced out stores. No xc global round-trip.            */
__global__ __launch_bounds__(256, 2) void k_attn_fused(
    const bf16* __restrict__ qw, const bf16* __restrict__ kw,
    const bf16* __restrict__ vw, const float* __restrict__ x,
    const bf16* __restrict__ pwb, const float* __restrict__ pwbeta,
    float* __restrict__ out) {
  __shared__ __align__(16) char smem[70656];
  /* map: [0,61440) ring | after loop: [0,33792) partials+l,
     [36864,69632) xc tile (64 rows x 512B, granule-swizzled),
     [69632,70656) beta | proj chunks reuse [0,32768) */
  const int orig = blockIdx.x;
  const int wg = (orig & 7) * 64 + (orig >> 3);  /* XCD j <- batch j */
  const int b = wg >> 6, qblk = wg & 63;
  const int t = threadIdx.x;
  const int wid = t >> 6, l = t & 63, ln = l & 31, g = l >> 5;
  const int m0 = wid * 1024;

  const bf16* qb = qw + (size_t)b * 4096 * 16;
  const char* kb = (const char*)(kw + (size_t)b * 4096 * 16);
  const char* vfb = (const char*)vw + (size_t)b * 524288;

  const char* kdma = kb + (size_t)m0 * 32 + (2 * ln + g) * 16;
  const char* vdma = vfb + (size_t)(m0 >> 5) * 4096 + l * 16;
  char* ring = smem + wid * 15360;

  const int nq = qblk * 64 + ln;
  const bf16x8 qf0 = *(const bf16x8*)(qb + (size_t)nq * 16 + g * 8);
  const bf16x8 qf1 = *(const bf16x8*)(qb + (size_t)(nq + 32) * 16 + g * 8);
  asm volatile("" :: "v"(qf0), "v"(qf1));

  f32x16 O00 = fzero16(), O01 = fzero16();
  f32x16 O10 = fzero16(), O11 = fzero16();
  float l0 = 0.f, l1 = 0.f;

#define ISSUE_TILE(TI, SLOT)                                  \
  do {                                                        \
    char* dst = ring + (SLOT) * 5120;                         \
    const char* ks = kdma + (size_t)(TI) * 1024;              \
    const char* vs = vdma + (size_t)(TI) * 4096;              \
    dma16(ks, dst);                                           \
    dma16(vs, dst + 1024);                                    \
    dma16(vs + 1024, dst + 2048);                             \
    dma16(vs + 2048, dst + 3072);                             \
    dma16(vs + 3072, dst + 4096);                             \
  } while (0)

  ISSUE_TILE(0, 0);
  ISSUE_TILE(1, 1);
  ISSUE_TILE(2, 2);

  int slot = 0;
#pragma unroll 1
  for (int it = 0; it < 32; ++it) {
    const int rem = 31 - it;
    if (rem >= 2)      { asm volatile("s_waitcnt vmcnt(10)" ::: "memory"); }
    else if (rem == 1) { asm volatile("s_waitcnt vmcnt(5)"  ::: "memory"); }
    else               { asm volatile("s_waitcnt vmcnt(0)"  ::: "memory"); }
    const char* rb = ring + slot * 5120 + l * 16;
    const uint4 kc = *(const uint4*)rb;
    const uint4 v0 = *(const uint4*)(rb + 1024);
    const uint4 v1 = *(const uint4*)(rb + 2048);
    const uint4 v2 = *(const uint4*)(rb + 3072);
    const uint4 v3 = *(const uint4*)(rb + 4096);
    asm volatile("s_waitcnt lgkmcnt(0)" ::: "memory");
    if (it + 3 < 32) ISSUE_TILE(it + 3, slot);
    const bf16x8 kf = __builtin_bit_cast(bf16x8, kc);
    f32x16 S0 = MFMA32(kf, qf0, fzero16(), 0, 0, 0);
    f32x16 S1 = MFMA32(kf, qf1, fzero16(), 0, 0, 0);
#pragma unroll
    for (int r = 0; r < 16; ++r) S0[r] = __builtin_amdgcn_exp2f(S0[r]);
#pragma unroll
    for (int r = 0; r < 16; ++r) S1[r] = __builtin_amdgcn_exp2f(S1[r]);
    {
      float a[8], c[8];
#pragma unroll
      for (int r = 0; r < 8; ++r) { a[r] = S0[2 * r] + S0[2 * r + 1];
                                    c[r] = S1[2 * r] + S1[2 * r + 1]; }
#pragma unroll
      for (int r = 0; r < 4; ++r) { a[r] = a[2 * r] + a[2 * r + 1];
                                    c[r] = c[2 * r] + c[2 * r + 1]; }
      l0 += (a[0] + a[1]) + (a[2] + a[3]);
      l1 += (c[0] + c[1]) + (c[2] + c[3]);
    }
    bf16x8 pa0, pa1, pc0, pc1;
#pragma unroll
    for (int r = 0; r < 8; ++r) {
      pa0[r] = (bf16)S0[r]; pa1[r] = (bf16)S0[r + 8];
      pc0[r] = (bf16)S1[r]; pc1[r] = (bf16)S1[r + 8];
    }
    O00 = MFMA32(__builtin_bit_cast(bf16x8, v0), pa0, O00, 0, 0, 0);
    O10 = MFMA32(__builtin_bit_cast(bf16x8, v0), pc0, O10, 0, 0, 0);
    O01 = MFMA32(__builtin_bit_cast(bf16x8, v1), pa0, O01, 0, 0, 0);
    O11 = MFMA32(__builtin_bit_cast(bf16x8, v1), pc0, O11, 0, 0, 0);
    O00 = MFMA32(__builtin_bit_cast(bf16x8, v2), pa1, O00, 0, 0, 0);
    O10 = MFMA32(__builtin_bit_cast(bf16x8, v2), pc1, O10, 0, 0, 0);
    O01 = MFMA32(__builtin_bit_cast(bf16x8, v3), pa1, O01, 0, 0, 0);
    O11 = MFMA32(__builtin_bit_cast(bf16x8, v3), pc1, O11, 0, 0, 0);
    slot = (slot == 2) ? 0 : slot + 1;
  }
#undef ISSUE_TILE
  l0 += __shfl_xor(l0, 32, 64);
  l1 += __shfl_xor(l1, 32, 64);

  __syncthreads();   /* ring dead; repartition LDS */

  /* partials: slice s = wid*2 + qsub (region [0,33792), R16 verbatim) */
  {
    const int msk = 2 * (ln & 7);
#pragma unroll
    for (int hq = 0; hq < 2; ++hq) {
      char* orow = smem + (wid * 2 + hq) * 4096 + ln * 128;
#pragma unroll
      for (int hc = 0; hc < 2; ++hc) {
        const f32x16& O = hq ? (hc ? O11 : O10) : (hc ? O01 : O00);
#pragma unroll
        for (int j = 0; j < 4; ++j) {
          bf16x4 e;
#pragma unroll
          for (int i = 0; i < 4; ++i) e[i] = (bf16)O[4 * j + i];
          const int chunk = hc * 8 + 2 * j + g;
          *(bf16x4*)(orow + ((chunk ^ msk) << 3)) = e;
        }
      }
      if (g == 0) *(float*)(smem + 32768 + (wid * 2 + hq) * 128 + ln * 4) = hq ? l1 : l0;
    }
  }

  /* prep_x2: relu(x2) -> bf16 pairs straight into xc tile cols 64:256
     (word col = (32+cp) ^ ((n&15)*4), granule-swizzle congruent)        */
  {
    unsigned* xcw = (unsigned*)(smem + 36864);   /* [64 n][128 words] */
    const float* xb = x + ((size_t)b * 256 + 64) * 4096 + qblk * 64;
#pragma unroll
    for (int i = 0; i < 6; ++i) {
      const int idx = i * 256 + t;
      const int cp = idx >> 4, f = idx & 15;
      const float4 a = *(const float4*)(xb + (size_t)(2 * cp) * 4096 + f * 4);
      const float4 c4 = *(const float4*)(xb + (size_t)(2 * cp + 1) * 4096 + f * 4);
      const float av[4] = {a.x, a.y, a.z, a.w};
      const float cv[4] = {c4.x, c4.y, c4.z, c4.w};
#pragma unroll
      for (int e = 0; e < 4; ++e) {
        const int n = f * 4 + e;
        const unsigned u =
            (unsigned)__builtin_bit_cast(unsigned short, (bf16)fmaxf(av[e], 0.f)) |
            ((unsigned)__builtin_bit_cast(unsigned short, (bf16)fmaxf(cv[e], 0.f)) << 16);
        xcw[n * 128 + ((32 + cp) ^ ((n & 15) * 4))] = u;
      }
    }
  }
  __syncthreads();

  /* combine partials -> xc tile cols 0:64 (granules k8 ^ (n&15)); beta */
  {
    const int n = t >> 3, k8 = t & 7;
    const int off = ((2 * k8) ^ (2 * (n & 7))) << 3;
    char* xcb = smem + 36864;
#pragma unroll
    for (int hq = 0; hq < 2; ++hq) {
      float L = 0.f;
      float acc[8];
#pragma unroll
      for (int e = 0; e < 8; ++e) acc[e] = 0.f;
#pragma unroll
      for (int kr_ = 0; kr_ < 4; ++kr_) {
        const int s = kr_ * 2 + hq;
        L += *(const float*)(smem + 32768 + s * 128 + n * 4);
        const bf16x8 v = *(const bf16x8*)(smem + s * 4096 + n * 128 + off);
#pragma unroll
        for (int e = 0; e < 8; ++e) acc[e] += (float)v[e];
      }
      const float rL = 1.0f / L;
      bf16x8 o8;
#pragma unroll
      for (int e = 0; e < 8; ++e) o8[e] = (bf16)fmaxf(acc[e] * rL, 0.f);
      const int n2 = hq * 32 + n;
      *(bf16x8*)(xcb + n2 * 512 + ((k8 ^ (n & 15)) * 16)) = o8;
    }
    ((float*)(smem + 69632))[t] = pwbeta[t];
  }
  __syncthreads();

  /* fused proj: 4 o-chunks of 64; per chunk stage 32KB pw' (k_proj swizzle),
     each wave = (osub = wid>>1, nsub = wid&1) -> one 32x32 acc, K=256.     */
  {
    bf16* pwlds = (bf16*)smem;
    const char* xcb = smem + 36864;
    const float* beta_l = (const float*)(smem + 69632);
    const int osub = wid >> 1, nsub = wid & 1;
    const int n2 = nsub * 32 + ln;
    float* ob = out + (size_t)b * 256 * 4096 + qblk * 64 + n2;
#pragma unroll 1
    for (int ch = 0; ch < 4; ++ch) {
      {  /* stage pw' chunk: thread t -> o = t>>2, 64-halfword segment t&3 */
        const int o = t >> 2, q4 = t & 3;
        const bf16* src = pwb + (size_t)(ch * 64 + o) * 256 + q4 * 64;
        const int sw = (o & 15) * 8;
#pragma unroll
        for (int j = 0; j < 8; ++j) {
          const bf16x8 v = *(const bf16x8*)(src + j * 8);
          *(bf16x8*)&pwlds[o * 256 + ((q4 * 64 + j * 8) ^ sw)] = v;
        }
      }
      __syncthreads();
      f32x16 acc = fzero16();
      const int o = osub * 32 + ln;
      const int swo = (o & 15) * 8;
#pragma unroll
      for (int ks = 0; ks < 16; ++ks) {
        const bf16x8 af = *(const bf16x8*)&pwlds[o * 256 + ((ks * 16 + g * 8) ^ swo)];
        const bf16x8 bf_ = *(const bf16x8*)(xcb + n2 * 512 +
                                            (((2 * ks + g) ^ (n2 & 15)) * 16));
        acc = MFMA32(af, bf_, acc, 0, 0, 0);
      }
#pragma unroll
      for (int r = 0; r < 16; ++r) {
        const int o_loc = (r & 3) + 8 * (r >> 2) + 4 * g;
        const int og = ch * 64 + osub * 32 + o_loc;
        ob[(size_t)og * 4096] = acc[r] + beta_l[og];
      }
      if (ch < 3) __syncthreads();
    }
  }
}

/* ---------------- host launcher ---------------- */
extern "C" void kernel_launch(void* const* d_in, const int* in_sizes, int n_in,
                              void* d_out, int out_size, void* d_ws, size_t ws_size,
                              hipStream_t stream) {
  (void)in_sizes; (void)n_in; (void)out_size; (void)ws_size;
  const float* x        = (const float*)d_in[0];
  const float* gn_g     = (const float*)d_in[1];
  const float* gn_b     = (const float*)d_in[2];
  const float* qkv_w    = (const float*)d_in[3];
  const float* qkv_bn_g = (const float*)d_in[4];
  const float* qkv_bn_b = (const float*)d_in[5];
  const float* qkv_rm   = (const float*)d_in[6];
  const float* qkv_rv   = (const float*)d_in[7];
  const float* proj_w   = (const float*)d_in[8];
  const float* proj_bn_g = (const float*)d_in[9];
  const float* proj_bn_b = (const float*)d_in[10];
  const float* proj_rm  = (const float*)d_in[11];
  const float* proj_rv  = (const float*)d_in[12];

  char* ws = (char*)d_ws;
  float* part   = (float*)ws;
  float* stats  = (float*)(ws + 4096);
  bf16* qw      = (bf16*)(ws + 8192);
  bf16* kw      = (bf16*)(ws + 8192 + (1u << 20));
  bf16* vw      = (bf16*)(ws + 8192 + (2u << 20));
  bf16* pwb     = (bf16*)(ws + 8192 + (6u << 20));
  float* pwbeta = (float*)(ws + 8192 + (6u << 20) + 131072);

  k_stats_partial<<<320, 256, 0, stream>>>(x, proj_w, proj_bn_g, proj_rv,
                                           proj_rm, proj_bn_b, part, pwb, pwbeta);
  k_stats_final<<<1, 256, 0, stream>>>(part, stats);
  k_qkv<<<512, 256, 0, stream>>>(x, gn_g, gn_b, qkv_w, qkv_bn_g, qkv_bn_b,
                                 qkv_rm, qkv_rv, stats, qw, kw, vw);
  k_attn_fused<<<512, 256, 0, stream>>>(qw, kw, vw, x, pwb, pwbeta,
                                        (float*)d_out);
}